// Round 5
// baseline (319.561 us; speedup 1.0000x reference)
//
#include <hip/hip_runtime.h>
#include <hip/hip_bf16.h>

#define M_   16384   // B*N tokens
#define K_   1024    // E
#define NQKV 3072    // 3*E output cols

typedef _Float16 f16x4 __attribute__((ext_vector_type(4)));
typedef _Float16 f16x8 __attribute__((ext_vector_type(8)));
typedef float    f32x4 __attribute__((ext_vector_type(4)));

// fp32 -> fp16 grid-stride convert (float4 granularity)
__global__ __launch_bounds__(256) void cvt_f32_f16(const float* __restrict__ in,
                                                   _Float16* __restrict__ o, int n4) {
  int i = blockIdx.x * blockDim.x + threadIdx.x;
  const int stride = gridDim.x * blockDim.x;
  for (; i < n4; i += stride) {
    float4 v = ((const float4*)in)[i];
    f16x4 h; h[0] = (_Float16)v.x; h[1] = (_Float16)v.y;
    h[2] = (_Float16)v.z; h[3] = (_Float16)v.w;
    *(f16x4*)&o[(size_t)i * 4] = h;
  }
}

// 3 weight matrices in one launch (blockIdx.y selects source)
__global__ __launch_bounds__(256) void cvt3_f32_f16(
    const float* __restrict__ a, const float* __restrict__ b,
    const float* __restrict__ c, _Float16* __restrict__ o, int n4each) {
  const float* src = (blockIdx.y == 0) ? a : (blockIdx.y == 1) ? b : c;
  _Float16* dst = o + (size_t)blockIdx.y * n4each * 4;
  int i = blockIdx.x * blockDim.x + threadIdx.x;
  const int stride = gridDim.x * blockDim.x;
  for (; i < n4each; i += stride) {
    float4 v = ((const float4*)src)[i];
    f16x4 h; h[0] = (_Float16)v.x; h[1] = (_Float16)v.y;
    h[2] = (_Float16)v.z; h[3] = (_Float16)v.w;
    *(f16x4*)&dst[(size_t)i * 4] = h;
  }
}

// 256x256-tile GEMM, fragment-prefetch pipeline, 2 barriers per K-tile.
// Quadrant order (a0,b0)->(a0,b1)->(a1,b1)->(a1,b0): each quadrant's new
// fragments are ds_read DURING the previous quadrant's MFMA cluster (LDS pipe
// overlaps matrix pipe; wave drift between the 2 barriers provides cross-wave
// overlap). Only b0 is live across the whole tile -> alternate b0e/b0o regs.
// Region A: rd b1(t) | stage all 8 gload_lds(t+1) | lgkm(4) q1 | rd a1(t) |
//           lgkm(8) q2 | vmcnt(4) | barrier
// Region B: rd a0(t+1) other buf | lgkm(8) q3 | rd b0next(t+1) | lgkm(4) q4 |
//           vmcnt(0) | barrier
// Visibility ledger: A0/B0(t+1) read in region B after all-waves vmcnt(4)+BAR;
// A1/B1(t+1) read in region A(t+1) after all-waves vmcnt(0)+BAR. WAR: staging
// into buf^1 at region A(t) is >=2 barriers after buf^1's last reads.
__global__ __launch_bounds__(512, 2) void gemm_qkv(
    const _Float16* __restrict__ xh, const _Float16* __restrict__ wh,
    const float* __restrict__ bq, const float* __restrict__ bk,
    const float* __restrict__ bv, _Float16* __restrict__ qkv)
{
  __shared__ __align__(16) _Float16 As[2][256 * 64];
  __shared__ __align__(16) _Float16 Bs[2][256 * 64];

  const int tid  = threadIdx.x;
  const int ln   = tid & 63;
  const int w    = tid >> 6;     // 0..7
  const int wm2  = w >> 2;       // 0..1
  const int wn4  = w & 3;        // 0..3
  const int lcol = ln & 15, quad = ln >> 4;

  const int bid = blockIdx.x;                   // 768 blocks
  const int swz = (bid & 7) * 96 + (bid >> 3);  // XCD-contiguous chunks
  const int m0 = (swz / 12) * 256;
  const int n0 = (swz % 12) * 256;

  f32x4 acc[8][4];
#pragma unroll
  for (int i = 0; i < 8; ++i)
#pragma unroll
    for (int j = 0; j < 4; ++j) acc[i][j] = f32x4{0.f, 0.f, 0.f, 0.f};

  f16x8 a0[4][2], a1[4][2], b0e[2][2], b0o[2][2], b1[2][2];

#define STAGE_A(BUF, KT, X)                                                    \
  { _Pragma("unroll")                                                          \
    for (int j = 0; j < 2; ++j) {                                              \
      const int c   = j * 512 + tid;                                           \
      const int rr  = c >> 3;                                                  \
      const int r   = (X) * 64 + (rr & 63) + ((rr >> 6) << 7);                 \
      const int cb  = (c & 7) ^ (r & 7);                                       \
      const int rr0 = j * 64 + w * 8;                                          \
      const int r0  = (X) * 64 + (rr0 & 63) + ((rr0 >> 6) << 7);               \
      __builtin_amdgcn_global_load_lds(                                        \
          (const __attribute__((address_space(1))) void*)(                     \
              xh + (size_t)(m0 + r) * K_ + (KT) * 64 + cb * 8),                \
          (__attribute__((address_space(3))) void*)(&As[BUF][r0 * 64]),        \
          16, 0, 0);                                                           \
    } }

#define STAGE_B(BUF, KT, Y)                                                    \
  { _Pragma("unroll")                                                          \
    for (int j = 0; j < 2; ++j) {                                              \
      const int c   = j * 512 + tid;                                           \
      const int rr  = c >> 3;                                                  \
      const int r   = ((rr >> 5) << 6) + (Y) * 32 + (rr & 31);                 \
      const int cb  = (c & 7) ^ (r & 7);                                       \
      const int rr0 = j * 64 + w * 8;                                          \
      const int r0  = ((rr0 >> 5) << 6) + (Y) * 32 + (rr0 & 31);               \
      __builtin_amdgcn_global_load_lds(                                        \
          (const __attribute__((address_space(1))) void*)(                     \
              wh + (size_t)(n0 + r) * K_ + (KT) * 64 + cb * 8),                \
          (__attribute__((address_space(3))) void*)(&Bs[BUF][r0 * 64]),        \
          16, 0, 0);                                                           \
    } }

  // fragment reads, both k-blocks: A-half = 8 ds_read_b128, B-half = 4
#define RDA(DST, BUF, MH)                                                      \
  _Pragma("unroll")                                                            \
  for (int mi = 0; mi < 4; ++mi) {                                             \
    const int ar = wm2 * 128 + (MH) * 64 + mi * 16 + lcol;                     \
    const int sw = ar & 7;                                                     \
    DST[mi][0] = *(const f16x8*)&As[BUF][ar * 64 + ((quad    ) ^ sw) * 8];     \
    DST[mi][1] = *(const f16x8*)&As[BUF][ar * 64 + ((quad + 4) ^ sw) * 8];     \
  }

#define RDB(DST, BUF, NH)                                                      \
  _Pragma("unroll")                                                            \
  for (int ni = 0; ni < 2; ++ni) {                                             \
    const int br = wn4 * 64 + (NH) * 32 + ni * 16 + lcol;                      \
    const int sw = br & 7;                                                     \
    DST[ni][0] = *(const f16x8*)&Bs[BUF][br * 64 + ((quad    ) ^ sw) * 8];     \
    DST[ni][1] = *(const f16x8*)&Bs[BUF][br * 64 + ((quad + 4) ^ sw) * 8];     \
  }

  // one C-quadrant x K=64: 16 MFMAs
#define MFMA16(AARR, BARR, MH, NH)                                             \
  __builtin_amdgcn_s_setprio(1);                                               \
  _Pragma("unroll")                                                            \
  for (int kb = 0; kb < 2; ++kb)                                               \
    _Pragma("unroll")                                                          \
    for (int mi = 0; mi < 4; ++mi)                                             \
      _Pragma("unroll")                                                        \
      for (int ni = 0; ni < 2; ++ni)                                           \
        acc[(MH) * 4 + mi][(NH) * 2 + ni] =                                    \
            __builtin_amdgcn_mfma_f32_16x16x32_f16(                            \
                AARR[mi][kb], BARR[ni][kb], acc[(MH) * 4 + mi][(NH) * 2 + ni], \
                0, 0, 0);                                                      \
  __builtin_amdgcn_s_setprio(0);

#define SB()    __builtin_amdgcn_sched_barrier(0)
#define BAR()   { __builtin_amdgcn_s_barrier(); SB(); }
#define LGKM(N) { asm volatile("s_waitcnt lgkmcnt(" #N ")" ::: "memory"); SB(); }
#define VM4()   { asm volatile("s_waitcnt vmcnt(4)" ::: "memory"); SB(); }
#define VM0()   { asm volatile("s_waitcnt vmcnt(0)" ::: "memory"); SB(); }

#define KTILE(CUR, B0C, B0N, T, NOTLAST)                                       \
  { /* ---- region A: q1 (a0,b0), q2 (a0,b1) ---- */                           \
    RDB(b1, CUR, 1); SB();                                                     \
    if (NOTLAST) {                                                             \
      STAGE_A(1 - (CUR), (T) + 1, 0); STAGE_B(1 - (CUR), (T) + 1, 0);          \
      STAGE_A(1 - (CUR), (T) + 1, 1); STAGE_B(1 - (CUR), (T) + 1, 1);          \
      SB();                                                                    \
    }                                                                          \
    LGKM(4);  MFMA16(a0, B0C, 0, 0);                                           \
    RDA(a1, CUR, 1); SB();                                                     \
    LGKM(8);  MFMA16(a0, b1, 0, 1);                                            \
    if (NOTLAST) VM4();                                                        \
    BAR();                                                                     \
    /* ---- region B: q3 (a1,b1), q4 (a1,b0) + prefetch t+1 (a0,b0) ---- */    \
    if (NOTLAST) { RDA(a0, 1 - (CUR), 0); SB(); LGKM(8); }                     \
    else         { LGKM(0); }                                                  \
    MFMA16(a1, b1, 1, 1);                                                      \
    if (NOTLAST) { RDB(B0N, 1 - (CUR), 0); SB(); LGKM(4); }                    \
    else         { LGKM(0); }                                                  \
    MFMA16(a1, B0C, 1, 0);                                                     \
    if (NOTLAST) VM0();                                                        \
    BAR();                                                                     \
  }

  // Prologue: stage tile 0 fully, drain, barrier, prefetch (a0,b0) of tile 0.
  STAGE_A(0, 0, 0); STAGE_B(0, 0, 0); STAGE_A(0, 0, 1); STAGE_B(0, 0, 1);
  VM0(); BAR();
  RDA(a0, 0, 0); SB(); RDB(b0e, 0, 0); SB();

#pragma unroll 1
  for (int it = 0; it < 7; ++it) {
    KTILE(0, b0e, b0o, it * 2,     1);
    KTILE(1, b0o, b0e, it * 2 + 1, 1);
  }
  KTILE(0, b0e, b0o, 14, 1);
  KTILE(1, b0o, b0e, 15, 0);

  // Epilogue: C/D col=lane&15, row=quad*4+reg. qkv[token*3072 + col].
#pragma unroll
  for (int nh = 0; nh < 4; ++nh) {
    const int col = n0 + wn4 * 64 + nh * 16 + lcol;
    const int seg = col >> 10, cs = col & 1023;
    const float bi = ((seg == 0) ? bq : (seg == 1) ? bk : bv)[cs];
#pragma unroll
    for (int mi = 0; mi < 8; ++mi) {
      const int r0 = m0 + wm2 * 128 + mi * 16 + quad * 4;
#pragma unroll
      for (int r = 0; r < 4; ++r)
        qkv[(size_t)(r0 + r) * 3072 + col] = (_Float16)(acc[mi][nh][r] + bi);
    }
  }
#undef STAGE_A
#undef STAGE_B
#undef RDA
#undef RDB
#undef MFMA16
#undef SB
#undef BAR
#undef LGKM
#undef VM4
#undef VM0
#undef KTILE
}

// One wave per token. qkv [token][3][1024] fp16. All global loads hoisted;
// pat read directly from global (L2-hot, no LDS/sync); PV uses 16x16x16 MFMA
// (K=16 exact: all 64 lanes active, no zero-padding, f16x4 operands).
__global__ __launch_bounds__(256) void attn_kernel(
    const _Float16* __restrict__ qkv,
    const float* __restrict__ pat,
    float* __restrict__ out)
{
  __shared__ __align__(16) _Float16 Ps[4][16 * 24];  // P[h][g], stride 24
  __shared__ __align__(16) _Float16 Vt[4][64 * 24];  // V^T[d][g], stride 24

  const int tid  = threadIdx.x;
  const int ln   = tid & 63;
  const int wv   = tid >> 6;
  const int lcol = ln & 15, quad = ln >> 4;
  const int t    = blockIdx.x * 4 + wv;

  const _Float16* qg = qkv + (size_t)t * 3072;
  const _Float16* kg = qg + 1024;
  const _Float16* vg = qg + 2048;

  // Issue every global load up front: V (2), Q (2), K (2), pat (4 scalar).
  f16x8 vc[2];
  vc[0] = *(const f16x8*)(vg + ((ln >> 3)    ) * 64 + (ln & 7) * 8);
  vc[1] = *(const f16x8*)(vg + ((ln >> 3) + 8) * 64 + (ln & 7) * 8);
  f16x8 aq0 = *(const f16x8*)(qg + lcol * 64 + quad * 8);
  f16x8 aq1 = *(const f16x8*)(qg + lcol * 64 + 32 + quad * 8);
  f16x8 bk0 = *(const f16x8*)(kg + lcol * 64 + quad * 8);
  f16x8 bk1 = *(const f16x8*)(kg + lcol * 64 + 32 + quad * 8);
  float p4[4];
#pragma unroll
  for (int r = 0; r < 4; r++) p4[r] = pat[(quad * 4 + r) * 16 + lcol];

  // Scatter V transposed into Vt[d][g] (wave-private, no barrier needed).
#pragma unroll
  for (int i = 0; i < 2; i++) {
    const int g = (ln >> 3) + i * 8, c = (ln & 7) * 8;
#pragma unroll
    for (int j = 0; j < 8; j++) Vt[wv][(c + j) * 24 + g] = vc[i][j];
  }

  // QK^T: A[m=h=lcol][k=quad*8+j], B[n=g=lcol][k=quad*8+j]
  f32x4 s = {0.f, 0.f, 0.f, 0.f};
  s = __builtin_amdgcn_mfma_f32_16x16x32_f16(aq0, bk0, s, 0, 0, 0);
  s = __builtin_amdgcn_mfma_f32_16x16x32_f16(aq1, bk1, s, 0, 0, 0);

  // lane holds scores[h=quad*4+r][g=lcol]; mask, softmax over g (16 lanes)
#pragma unroll
  for (int r = 0; r < 4; r++) {
    const float sv = s[r] * p4[r];
    float m = sv;
#pragma unroll
    for (int msk = 1; msk < 16; msk <<= 1) m = fmaxf(m, __shfl_xor(m, msk, 64));
    const float e = __expf(sv - m);
    float su = e;
#pragma unroll
    for (int msk = 1; msk < 16; msk <<= 1) su += __shfl_xor(su, msk, 64);
    Ps[wv][(quad * 4 + r) * 24 + lcol] = (_Float16)(e / su);
  }

  // PV with 16x16x16 (K=16): A[m=h=lcol][k=g=quad*4+j] from Ps;
  // B[n=d][k=g=quad*4+j] from Vt. All lanes active.
  f16x4 ap = *(const f16x4*)&Ps[wv][lcol * 24 + quad * 4];

  f32x4 o[4];
#pragma unroll
  for (int dt = 0; dt < 4; dt++) {
    f16x4 bvf = *(const f16x4*)&Vt[wv][(dt * 16 + lcol) * 24 + quad * 4];
    f32x4 z = {0.f, 0.f, 0.f, 0.f};
    o[dt] = __builtin_amdgcn_mfma_f32_16x16x16f16(ap, bvf, z, 0, 0, 0);
  }

  // C layout: row h=quad*4+r, col d=dt*16+lcol
  float* op = out + (size_t)t * 1024;
#pragma unroll
  for (int dt = 0; dt < 4; dt++)
#pragma unroll
    for (int r = 0; r < 4; r++)
      op[(quad * 4 + r) * 64 + dt * 16 + lcol] = o[dt][r];
}

extern "C" void kernel_launch(void* const* d_in, const int* in_sizes, int n_in,
                              void* d_out, int out_size, void* d_ws, size_t ws_size,
                              hipStream_t stream) {
  const float* x   = (const float*)d_in[0];
  const float* pat = (const float*)d_in[1];
  const float* Wq  = (const float*)d_in[2];
  const float* bq  = (const float*)d_in[3];
  const float* Wk  = (const float*)d_in[4];
  const float* bk  = (const float*)d_in[5];
  const float* Wv  = (const float*)d_in[6];
  const float* bv  = (const float*)d_in[7];

  // ws layout (f16 elements):
  //   qkvh [16384][3][1024]  @ 0           (96 MiB)
  //   xh   [16384][1024]     @ 50331648    (32 MiB)
  //   wh   [3][1024][1024]   @ 67108864    ( 6 MiB)   total ~134 MiB
  _Float16* qkvh = (_Float16*)d_ws;
  _Float16* xh   = qkvh + (size_t)50331648;
  _Float16* wh   = qkvh + (size_t)67108864;

  cvt_f32_f16<<<4096, 256, 0, stream>>>(x, xh, 4194304);
  cvt3_f32_f16<<<dim3(256, 3), 256, 0, stream>>>(Wq, Wk, Wv, wh, 262144);

  // 64 m-tiles x 12 n-tiles = 768 blocks, 512 threads (8 waves)
  gemm_qkv<<<768, 512, 0, stream>>>(xh, wh, bq, bk, bv, qkvh);
  attn_kernel<<<M_ / 4, 256, 0, stream>>>(qkvh, pat, (float*)d_out);
}

// Round 6
// 259.459 us; speedup vs baseline: 1.2316x; 1.2316x over previous
//
#include <hip/hip_runtime.h>
#include <hip/hip_bf16.h>

#define M_   16384   // B*N tokens
#define K_   1024    // E
#define NQKV 3072    // 3*E output cols

typedef _Float16 f16x4 __attribute__((ext_vector_type(4)));
typedef _Float16 f16x8 __attribute__((ext_vector_type(8)));
typedef float    f32x4 __attribute__((ext_vector_type(4)));

// fp32 -> fp16 grid-stride convert (float4 granularity)
__global__ __launch_bounds__(256) void cvt_f32_f16(const float* __restrict__ in,
                                                   _Float16* __restrict__ o, int n4) {
  int i = blockIdx.x * blockDim.x + threadIdx.x;
  const int stride = gridDim.x * blockDim.x;
  for (; i < n4; i += stride) {
    float4 v = ((const float4*)in)[i];
    f16x4 h; h[0] = (_Float16)v.x; h[1] = (_Float16)v.y;
    h[2] = (_Float16)v.z; h[3] = (_Float16)v.w;
    *(f16x4*)&o[(size_t)i * 4] = h;
  }
}

// 3 weight matrices in one launch (blockIdx.y selects source)
__global__ __launch_bounds__(256) void cvt3_f32_f16(
    const float* __restrict__ a, const float* __restrict__ b,
    const float* __restrict__ c, _Float16* __restrict__ o, int n4each) {
  const float* src = (blockIdx.y == 0) ? a : (blockIdx.y == 1) ? b : c;
  _Float16* dst = o + (size_t)blockIdx.y * n4each * 4;
  int i = blockIdx.x * blockDim.x + threadIdx.x;
  const int stride = gridDim.x * blockDim.x;
  for (; i < n4each; i += stride) {
    float4 v = ((const float4*)src)[i];
    f16x4 h; h[0] = (_Float16)v.x; h[1] = (_Float16)v.y;
    h[2] = (_Float16)v.z; h[3] = (_Float16)v.w;
    *(f16x4*)&dst[(size_t)i * 4] = h;
  }
}

// 256x256-tile 8-phase GEMM, counted vmcnt AND counted lgkmcnt (R3 structure,
// measured 123.6us / MfmaUtil 36.6 / 0 bank conflicts - reverted from the R5
// fragment-prefetch variant which spilled: 96->112 frag VGPRs pushed the
// 249/256 budget over, +90MB scratch HBM traffic).
// Phase reads: ph1{B0,A0}=12, ph2{A1}=8, ph3{B1}=4, ph4{0}. Each phase:
// issue kb0 reads | kb1 reads | stage -> barrier -> lgkmcnt(N) -> 8 MFMA ->
// lgkmcnt(0) -> 8 MFMA -> barrier. vmcnt(6) only at ph4/ph8.
// Epilogue: nh INNERMOST so each quad writes 4x32B back-to-back covering one
// full 128B line (WRITE_SIZE was 148MB vs 100MB ideal from partial lines).
__global__ __launch_bounds__(512, 2) void gemm_qkv(
    const _Float16* __restrict__ xh, const _Float16* __restrict__ wh,
    const float* __restrict__ bq, const float* __restrict__ bk,
    const float* __restrict__ bv, _Float16* __restrict__ qkv)
{
  __shared__ __align__(16) _Float16 As[2][256 * 64];
  __shared__ __align__(16) _Float16 Bs[2][256 * 64];

  const int tid  = threadIdx.x;
  const int ln   = tid & 63;
  const int w    = tid >> 6;     // 0..7
  const int wm2  = w >> 2;       // 0..1
  const int wn4  = w & 3;        // 0..3
  const int lcol = ln & 15, quad = ln >> 4;

  const int bid = blockIdx.x;                   // 768 blocks
  const int swz = (bid & 7) * 96 + (bid >> 3);  // XCD-contiguous chunks
  const int m0 = (swz / 12) * 256;
  const int n0 = (swz % 12) * 256;

  f32x4 acc[8][4];
#pragma unroll
  for (int i = 0; i < 8; ++i)
#pragma unroll
    for (int j = 0; j < 4; ++j) acc[i][j] = f32x4{0.f, 0.f, 0.f, 0.f};

  f16x8 a0[4][2], a1[4][2], b0[2][2], b1[2][2];

#define STAGE_A(BUF, KT, X)                                                    \
  { _Pragma("unroll")                                                          \
    for (int j = 0; j < 2; ++j) {                                              \
      const int c   = j * 512 + tid;                                           \
      const int rr  = c >> 3;                                                  \
      const int r   = (X) * 64 + (rr & 63) + ((rr >> 6) << 7);                 \
      const int cb  = (c & 7) ^ (r & 7);                                       \
      const int rr0 = j * 64 + w * 8;                                          \
      const int r0  = (X) * 64 + (rr0 & 63) + ((rr0 >> 6) << 7);               \
      __builtin_amdgcn_global_load_lds(                                        \
          (const __attribute__((address_space(1))) void*)(                     \
              xh + (size_t)(m0 + r) * K_ + (KT) * 64 + cb * 8),                \
          (__attribute__((address_space(3))) void*)(&As[BUF][r0 * 64]),        \
          16, 0, 0);                                                           \
    } }

#define STAGE_B(BUF, KT, Y)                                                    \
  { _Pragma("unroll")                                                          \
    for (int j = 0; j < 2; ++j) {                                              \
      const int c   = j * 512 + tid;                                           \
      const int rr  = c >> 3;                                                  \
      const int r   = ((rr >> 5) << 6) + (Y) * 32 + (rr & 31);                 \
      const int cb  = (c & 7) ^ (r & 7);                                       \
      const int rr0 = j * 64 + w * 8;                                          \
      const int r0  = ((rr0 >> 5) << 6) + (Y) * 32 + (rr0 & 31);               \
      __builtin_amdgcn_global_load_lds(                                        \
          (const __attribute__((address_space(1))) void*)(                     \
              wh + (size_t)(n0 + r) * K_ + (KT) * 64 + cb * 8),                \
          (__attribute__((address_space(3))) void*)(&Bs[BUF][r0 * 64]),        \
          16, 0, 0);                                                           \
    } }

  // fragment reads, per k-block KB (0/1): A = 4 ds_read_b128, B = 2
#define RDA(DST, BUF, MH, KB)                                                  \
  _Pragma("unroll")                                                            \
  for (int mi = 0; mi < 4; ++mi) {                                             \
    const int ar = wm2 * 128 + (MH) * 64 + mi * 16 + lcol;                     \
    const int sw = ar & 7;                                                     \
    DST[mi][KB] = *(const f16x8*)&As[BUF][ar * 64 + (((KB)*4 + quad) ^ sw) * 8]; \
  }

#define RDB(DST, BUF, NH, KB)                                                  \
  _Pragma("unroll")                                                            \
  for (int ni = 0; ni < 2; ++ni) {                                             \
    const int br = wn4 * 64 + (NH) * 32 + ni * 16 + lcol;                      \
    const int sw = br & 7;                                                     \
    DST[ni][KB] = *(const f16x8*)&Bs[BUF][br * 64 + (((KB)*4 + quad) ^ sw) * 8]; \
  }

#define MFMA8(AARR, BARR, MH, NH, KB)                                          \
  __builtin_amdgcn_s_setprio(1);                                               \
  _Pragma("unroll")                                                            \
  for (int mi = 0; mi < 4; ++mi)                                               \
    _Pragma("unroll")                                                          \
    for (int ni = 0; ni < 2; ++ni)                                             \
      acc[(MH) * 4 + mi][(NH) * 2 + ni] =                                      \
          __builtin_amdgcn_mfma_f32_16x16x32_f16(                              \
              AARR[mi][KB], BARR[ni][KB], acc[(MH) * 4 + mi][(NH) * 2 + ni],   \
              0, 0, 0);                                                        \
  __builtin_amdgcn_s_setprio(0);

#define SB()    __builtin_amdgcn_sched_barrier(0)
#define BAR()   { __builtin_amdgcn_s_barrier(); SB(); }
#define LGKM(N) { asm volatile("s_waitcnt lgkmcnt(" #N ")" ::: "memory"); SB(); }
#define VM6()   asm volatile("s_waitcnt vmcnt(6)" ::: "memory")
#define VM0()   asm volatile("s_waitcnt vmcnt(0)" ::: "memory")

  // 4 phases for one K-tile in BUF; STG1..4 are the stage ops for each phase.
#define KTILE(BUF, STG1, STG2, STG3, STG4, WAIT4)                              \
  { /* ph1: B0 + A0 (12 reads) */                                              \
    RDB(b0, BUF, 0, 0); RDA(a0, BUF, 0, 0); SB();                              \
    RDB(b0, BUF, 0, 1); RDA(a0, BUF, 0, 1); SB();                              \
    STG1;                                                                      \
    BAR(); LGKM(6);  MFMA8(a0, b0, 0, 0, 0);                                   \
           LGKM(0);  MFMA8(a0, b0, 0, 0, 1); BAR();                            \
    /* ph2: A1 (8 reads) */                                                    \
    RDA(a1, BUF, 1, 0); SB(); RDA(a1, BUF, 1, 1); SB();                        \
    STG2;                                                                      \
    BAR(); LGKM(4);  MFMA8(a1, b0, 1, 0, 0);                                   \
           LGKM(0);  MFMA8(a1, b0, 1, 0, 1); BAR();                            \
    /* ph3: B1 (4 reads) */                                                    \
    RDB(b1, BUF, 1, 0); SB(); RDB(b1, BUF, 1, 1); SB();                        \
    STG3;                                                                      \
    BAR(); LGKM(2);  MFMA8(a1, b1, 1, 1, 0);                                   \
           LGKM(0);  MFMA8(a1, b1, 1, 1, 1); BAR();                            \
    /* ph4: no reads, pure MFMA */                                             \
    STG4; WAIT4;                                                               \
    BAR();           MFMA8(a0, b1, 0, 1, 0);                                   \
                     MFMA8(a0, b1, 0, 1, 1); BAR();                            \
  }

  // Prologue: buf0 = kt0 full, buf1 = kt1 {B0, A1, B1} (A0 arrives iter0-ph1)
  STAGE_A(0, 0, 0); STAGE_B(0, 0, 0); STAGE_A(0, 0, 1); STAGE_B(0, 0, 1);
  STAGE_B(1, 1, 0); STAGE_A(1, 1, 1); STAGE_B(1, 1, 1);
  VM6(); BAR();

#pragma unroll 1
  for (int it = 0; it < 7; ++it) {
    const int kt = it * 2;
    KTILE(0, STAGE_A(1, kt + 1, 0), STAGE_B(0, kt + 2, 0),
             STAGE_A(0, kt + 2, 1), STAGE_B(0, kt + 2, 1), VM6());
    KTILE(1, STAGE_A(0, kt + 2, 0), STAGE_B(1, kt + 3, 0),
             STAGE_A(1, kt + 3, 1), STAGE_B(1, kt + 3, 1), VM6());
  }
  // last iteration (kt=14): only buf1.A0 (kt 15) still needs staging
  KTILE(0, STAGE_A(1, 15, 0), , , , VM0());
  KTILE(1, , , , , );

  // Epilogue. C/D: col=lane&15, row=quad*4+reg. Loop order mi -> r -> nh so a
  // quad's 4 nh-stores (32B each) land back-to-back covering one 128B line.
  float bi4[4];
#pragma unroll
  for (int nh = 0; nh < 4; ++nh) {
    const int col = n0 + wn4 * 64 + nh * 16 + lcol;
    const int seg = col >> 10, cs = col & 1023;
    bi4[nh] = ((seg == 0) ? bq : (seg == 1) ? bk : bv)[cs];
  }
#pragma unroll
  for (int mi = 0; mi < 8; ++mi) {
    const int r0 = m0 + wm2 * 128 + mi * 16 + quad * 4;
#pragma unroll
    for (int r = 0; r < 4; ++r) {
      _Float16* rowp = qkv + (size_t)(r0 + r) * 3072 + n0 + wn4 * 64 + lcol;
#pragma unroll
      for (int nh = 0; nh < 4; ++nh)
        rowp[nh * 16] = (_Float16)(acc[mi][nh][r] + bi4[nh]);
    }
  }
#undef STAGE_A
#undef STAGE_B
#undef RDA
#undef RDB
#undef MFMA8
#undef SB
#undef BAR
#undef LGKM
#undef VM6
#undef VM0
#undef KTILE
}

// One wave per token. qkv [token][3][1024] fp16. All global loads hoisted;
// pat read directly from global (L2-hot, no LDS/sync); PV uses 16x16x16 MFMA
// (K=16 exact: all 64 lanes active). Output stores: dt INNERMOST so each
// quad-row's 4x64B stores are consecutive (full-line write coalescing).
__global__ __launch_bounds__(256) void attn_kernel(
    const _Float16* __restrict__ qkv,
    const float* __restrict__ pat,
    float* __restrict__ out)
{
  __shared__ __align__(16) _Float16 Ps[4][16 * 24];  // P[h][g], stride 24
  __shared__ __align__(16) _Float16 Vt[4][64 * 24];  // V^T[d][g], stride 24

  const int tid  = threadIdx.x;
  const int ln   = tid & 63;
  const int wv   = tid >> 6;
  const int lcol = ln & 15, quad = ln >> 4;
  const int t    = blockIdx.x * 4 + wv;

  const _Float16* qg = qkv + (size_t)t * 3072;
  const _Float16* kg = qg + 1024;
  const _Float16* vg = qg + 2048;

  // Issue every global load up front: V (2), Q (2), K (2), pat (4 scalar).
  f16x8 vc[2];
  vc[0] = *(const f16x8*)(vg + ((ln >> 3)    ) * 64 + (ln & 7) * 8);
  vc[1] = *(const f16x8*)(vg + ((ln >> 3) + 8) * 64 + (ln & 7) * 8);
  f16x8 aq0 = *(const f16x8*)(qg + lcol * 64 + quad * 8);
  f16x8 aq1 = *(const f16x8*)(qg + lcol * 64 + 32 + quad * 8);
  f16x8 bk0 = *(const f16x8*)(kg + lcol * 64 + quad * 8);
  f16x8 bk1 = *(const f16x8*)(kg + lcol * 64 + 32 + quad * 8);
  float p4[4];
#pragma unroll
  for (int r = 0; r < 4; r++) p4[r] = pat[(quad * 4 + r) * 16 + lcol];

  // Scatter V transposed into Vt[d][g] (wave-private, no barrier needed).
#pragma unroll
  for (int i = 0; i < 2; i++) {
    const int g = (ln >> 3) + i * 8, c = (ln & 7) * 8;
#pragma unroll
    for (int j = 0; j < 8; j++) Vt[wv][(c + j) * 24 + g] = vc[i][j];
  }

  // QK^T: A[m=h=lcol][k=quad*8+j], B[n=g=lcol][k=quad*8+j]
  f32x4 s = {0.f, 0.f, 0.f, 0.f};
  s = __builtin_amdgcn_mfma_f32_16x16x32_f16(aq0, bk0, s, 0, 0, 0);
  s = __builtin_amdgcn_mfma_f32_16x16x32_f16(aq1, bk1, s, 0, 0, 0);

  // lane holds scores[h=quad*4+r][g=lcol]; mask, softmax over g (16 lanes)
#pragma unroll
  for (int r = 0; r < 4; r++) {
    const float sv = s[r] * p4[r];
    float m = sv;
#pragma unroll
    for (int msk = 1; msk < 16; msk <<= 1) m = fmaxf(m, __shfl_xor(m, msk, 64));
    const float e = __expf(sv - m);
    float su = e;
#pragma unroll
    for (int msk = 1; msk < 16; msk <<= 1) su += __shfl_xor(su, msk, 64);
    Ps[wv][(quad * 4 + r) * 24 + lcol] = (_Float16)(e / su);
  }

  // PV with 16x16x16 (K=16): A[m=h=lcol][k=g=quad*4+j] from Ps;
  // B[n=d][k=g=quad*4+j] from Vt. All lanes active.
  f16x4 ap = *(const f16x4*)&Ps[wv][lcol * 24 + quad * 4];

  f32x4 o[4];
#pragma unroll
  for (int dt = 0; dt < 4; dt++) {
    f16x4 bvf = *(const f16x4*)&Vt[wv][(dt * 16 + lcol) * 24 + quad * 4];
    f32x4 z = {0.f, 0.f, 0.f, 0.f};
    o[dt] = __builtin_amdgcn_mfma_f32_16x16x16f16(ap, bvf, z, 0, 0, 0);
  }

  // C layout: row h=quad*4+r, col d=dt*16+lcol. dt innermost: 4 consecutive
  // 64B pieces of one 256B row region per (r).
  float* op = out + (size_t)t * 1024;
#pragma unroll
  for (int r = 0; r < 4; r++) {
    float* rp = op + (quad * 4 + r) * 64 + lcol;
#pragma unroll
    for (int dt = 0; dt < 4; dt++)
      rp[dt * 16] = o[dt][r];
  }
}

extern "C" void kernel_launch(void* const* d_in, const int* in_sizes, int n_in,
                              void* d_out, int out_size, void* d_ws, size_t ws_size,
                              hipStream_t stream) {
  const float* x   = (const float*)d_in[0];
  const float* pat = (const float*)d_in[1];
  const float* Wq  = (const float*)d_in[2];
  const float* bq  = (const float*)d_in[3];
  const float* Wk  = (const float*)d_in[4];
  const float* bk  = (const float*)d_in[5];
  const float* Wv  = (const float*)d_in[6];
  const float* bv  = (const float*)d_in[7];

  // ws layout (f16 elements):
  //   qkvh [16384][3][1024]  @ 0           (96 MiB)
  //   xh   [16384][1024]     @ 50331648    (32 MiB)
  //   wh   [3][1024][1024]   @ 67108864    ( 6 MiB)   total ~134 MiB
  _Float16* qkvh = (_Float16*)d_ws;
  _Float16* xh   = qkvh + (size_t)50331648;
  _Float16* wh   = qkvh + (size_t)67108864;

  cvt_f32_f16<<<4096, 256, 0, stream>>>(x, xh, 4194304);
  cvt3_f32_f16<<<dim3(256, 3), 256, 0, stream>>>(Wq, Wk, Wv, wh, 262144);

  // 64 m-tiles x 12 n-tiles = 768 blocks, 512 threads (8 waves)
  gemm_qkv<<<768, 512, 0, stream>>>(xh, wh, bq, bk, bv, qkvh);
  attn_kernel<<<M_ / 4, 256, 0, stream>>>(qkvh, pat, (float*)d_out);
}